// Round 9
// baseline (634.512 us; speedup 1.0000x reference)
//
#include <hip/hip_runtime.h>

typedef unsigned short ushort_t;
typedef unsigned int   u32;
typedef __attribute__((ext_vector_type(8))) short bf16x8;
typedef __attribute__((ext_vector_type(4))) float f32x4;

#define NNODES 100000
#define DIM    256
#define NEDGE  300000
#define KSTEPS 16           // BK = 32 over virtual K = [agg | xin] = 512
#define BROWS  128          // rows per block (4 row-groups x 32 rows)
#define WCT    8            // col-tiles per wave (N split across 2 col-groups)
#define SLICE  16384        // ushorts per 32-k B slice: 2 planes x 256 n x 32 k
// B slice layout (ushort units): plane*8192 + ct*512 + q*128 + nn*8 + j
// A tensors (x2 / h / agg2) are split-bf16 planes: row = [256 hi ushorts | 256 lo ushorts]
#define MFMA16 __builtin_amdgcn_mfma_f32_16x16x32_bf16

// ================= CSR build (counting sort by dst) =================

__global__ void count_kernel(const int* __restrict__ dst, int* __restrict__ cnt, int E) {
    int e = blockIdx.x * blockDim.x + threadIdx.x;
    if (e < E) atomicAdd(&cnt[dst[e]], 1);
}

__global__ void scan1(const int* __restrict__ cnt, int* __restrict__ partial, int n) {
    __shared__ int s[256];
    int i = blockIdx.x * 256 + threadIdx.x;
    s[threadIdx.x] = (i < n) ? cnt[i] : 0;
    __syncthreads();
    for (int off = 128; off > 0; off >>= 1) {
        if (threadIdx.x < off) s[threadIdx.x] += s[threadIdx.x + off];
        __syncthreads();
    }
    if (threadIdx.x == 0) partial[blockIdx.x] = s[0];
}

__global__ void scan2(int* __restrict__ partial, int nb) {
    __shared__ int s[512];
    int t = threadIdx.x;
    int orig = (t < nb) ? partial[t] : 0;
    s[t] = orig;
    __syncthreads();
    for (int off = 1; off < 512; off <<= 1) {
        int v = (t >= off) ? s[t - off] : 0;
        __syncthreads();
        s[t] += v;
        __syncthreads();
    }
    if (t < nb) partial[t] = s[t] - orig;  // exclusive
}

__global__ void scan3(const int* __restrict__ cnt, const int* __restrict__ partial,
                      int* __restrict__ row_start, int n) {
    __shared__ int s[256];
    int i = blockIdx.x * 256 + threadIdx.x;
    int v = (i < n) ? cnt[i] : 0;
    s[threadIdx.x] = v;
    __syncthreads();
    for (int off = 1; off < 256; off <<= 1) {
        int t = (threadIdx.x >= off) ? s[threadIdx.x - off] : 0;
        __syncthreads();
        s[threadIdx.x] += t;
        __syncthreads();
    }
    if (i < n) row_start[i] = partial[blockIdx.x] + s[threadIdx.x] - v;
}

__global__ void fill_csr(const int* __restrict__ src, const int* __restrict__ dst,
                         const int* __restrict__ row_start, int* __restrict__ cursor,
                         int* __restrict__ esrc, int E) {
    int e = blockIdx.x * blockDim.x + threadIdx.x;
    if (e < E) {
        int d = dst[e];
        int pos = row_start[d] + atomicAdd(&cursor[d], 1);
        esrc[pos] = src[e];
    }
}

// ================= split helpers =================

__device__ __forceinline__ float bfhi(unsigned u) { return __uint_as_float(u << 16); }
__device__ __forceinline__ float bflo(unsigned u) { return __uint_as_float(u & 0xFFFF0000u); }

// split 4 floats -> packed hi uint2 + lo uint2 (truncating split)
__device__ __forceinline__ void split4pack(float v0, float v1, float v2, float v3,
                                           uint2& hi, uint2& lo) {
    unsigned u0 = __float_as_uint(v0), u1 = __float_as_uint(v1);
    unsigned u2 = __float_as_uint(v2), u3 = __float_as_uint(v3);
    hi.x = (u0 >> 16) | (u1 & 0xFFFF0000u);
    hi.y = (u2 >> 16) | (u3 & 0xFFFF0000u);
    unsigned w0 = __float_as_uint(v0 - bflo(u0)), w1 = __float_as_uint(v1 - bflo(u1));
    unsigned w2 = __float_as_uint(v2 - bflo(u2)), w3 = __float_as_uint(v3 - bflo(u3));
    lo.x = (w0 >> 16) | (w1 & 0xFFFF0000u);
    lo.y = (w2 >> 16) | (w3 & 0xFFFF0000u);
}

// ================= x -> split-plane form (one-time) =================
__global__ __launch_bounds__(256) void split_x(const float* __restrict__ x,
                                               ushort_t* __restrict__ x2) {
    int idx = blockIdx.x * 256 + threadIdx.x;      // node*64 + lane
    if (idx >= NNODES * 64) return;
    int node = idx >> 6, lane = idx & 63;
    float4 v = ((const float4*)(x + (size_t)node * DIM))[lane];
    uint2 hi, lo;
    split4pack(v.x, v.y, v.z, v.w, hi, lo);
    *(uint2*)(x2 + (size_t)node * 512 + lane * 4)       = hi;
    *(uint2*)(x2 + (size_t)node * 512 + 256 + lane * 4) = lo;
}

// ================= aggregation: one wave per node, split-plane in/out =================
__global__ __launch_bounds__(256) void aggregate2(
    const int* __restrict__ esrc, const int* __restrict__ row_start,
    const int* __restrict__ cnt, const ushort_t* __restrict__ x2,
    ushort_t* __restrict__ agg2)
{
    int node = (blockIdx.x * blockDim.x + threadIdx.x) >> 6;
    int lane = threadIdx.x & 63;
    if (node >= NNODES) return;
    int start = row_start[node];
    int c = cnt[node];
    float a0 = 0.f, a1 = 0.f, a2 = 0.f, a3 = 0.f;
    for (int i = 0; i < c; i++) {
        int s = esrc[start + i];
        const uint2 h = *(const uint2*)(x2 + (size_t)s * 512 + lane * 4);
        const uint2 l = *(const uint2*)(x2 + (size_t)s * 512 + 256 + lane * 4);
        a0 += bfhi(h.x) + bfhi(l.x);
        a1 += bflo(h.x) + bflo(l.x);
        a2 += bfhi(h.y) + bfhi(l.y);
        a3 += bflo(h.y) + bflo(l.y);
    }
    float inv = (c > 0) ? 1.0f / (float)c : 0.0f;
    uint2 hi, lo;
    split4pack(a0 * inv, a1 * inv, a2 * inv, a3 * inv, hi, lo);
    *(uint2*)(agg2 + (size_t)node * 512 + lane * 4)       = hi;
    *(uint2*)(agg2 + (size_t)node * 512 + 256 + lane * 4) = lo;
}

// ========== weight split + swizzle into MFMA-fragment/LDS-linear order ==========
__global__ void conv_weights(const float* __restrict__ Wl, const float* __restrict__ Wr,
                             ushort_t* __restrict__ Bsw) {
    int idx = blockIdx.x * 256 + threadIdx.x;      // n*512 + k
    if (idx >= 256 * 512) return;
    int n = idx >> 9, k = idx & 511;
    float v = (k < DIM) ? Wl[n * DIM + k] : Wr[n * DIM + (k - DIM)];
    unsigned u = __float_as_uint(v);
    float lo = v - bflo(u);
    int ks = k >> 5, q = (k >> 3) & 3, j = k & 7;
    int ct = n >> 4, nn = n & 15;
    int base = ks * SLICE + ct * 512 + q * 128 + nn * 8 + j;
    Bsw[base]        = (ushort_t)(u >> 16);                      // hi plane
    Bsw[base + 8192] = (ushort_t)(__float_as_uint(lo) >> 16);    // lo plane
}

// ================= GEMM helpers =================

// Async direct global->LDS staging of one 32 KB B slice by a 512-thread block.
// 2048 chunks of 16 B; 4 DMA instructions per thread (uniform vmcnt contribution).
__device__ __forceinline__ void stage_b_async(const ushort_t* __restrict__ slice,
                                              ushort_t* buf, int tid) {
    const int wave = tid >> 6;
    #pragma unroll
    for (int i = 0; i < 4; i++) {
        const int c  = tid + i * 512;            // per-lane 16B chunk index
        const int cb = wave * 64 + i * 512;      // wave-uniform base chunk
        __builtin_amdgcn_global_load_lds(
            (const __attribute__((address_space(1))) u32*)(slice + (size_t)c * 8),
            (__attribute__((address_space(3))) u32*)(buf + cb * 8),
            16, 0, 0);
    }
}

// A fragments come pre-split: 4 x 16B loads (row0 hi, row0 lo, row1 hi, row1 lo).
// Rows pre-clamped -> unconditional, uniform vmcnt counts across waves.
__device__ __forceinline__ void load_afrag(const ushort_t* __restrict__ base,
                                           int r0, int r1, int kk, bf16x8* f) {
    const ushort_t* p0 = base + (size_t)r0 * 512 + kk;
    const ushort_t* p1 = base + (size_t)r1 * 512 + kk;
    f[0] = *(const bf16x8*)(p0);
    f[1] = *(const bf16x8*)(p0 + 256);
    f[2] = *(const bf16x8*)(p1);
    f[3] = *(const bf16x8*)(p1 + 256);
}

// ================= MFMA GEMM: out = [agg|xin] @ B^T + bias (split-bf16, fp32 acc) ===============
// m201 RESOURCE SHAPE: 512 threads / 8 waves, ONE block per CU (128 KB LDS), 2 waves/SIMD
// with a 256-VGPR budget (__launch_bounds__(512,2)). B lives in a 4-slice LDS ring staged
// THREE slices ahead; A frags 2-deep. Top-of-step wait is fully counted:
//   steady state (ks<=13): vmcnt(8)  — leaves {B[ks+2] 4 DMA, A[ks+1] 4 loads} in flight,
//                                      forces B[ks+1] (staged 2 steps ago) + A[ks] complete.
//   ks==14: vmcnt(4); ks==15: vmcnt(0)   (issue guards break the pattern at the tail).
// Cross-wave LDS visibility: each wave vmcnt-forces its own B[s] DMAs one step early, and the
// single per-step s_barrier publishes them before any wave reads slice s.
// Mechanisms vs the 128-us plateau: (i) one barrier group per CU (no cross-block LDS/phase
// interference), (ii) B flight time >= 2 full k-steps (transient DMA delay off critical path),
// (iii) 782 blocks at 1/CU = 3.05 rounds -> tail waste ~2% (was ~20% at 1.53 rounds).
// Output written in-place over xin2 (block-own rows; __syncthreads before epilogue).
__global__ __launch_bounds__(512, 2) void sage_gemm_mfma(
    const ushort_t* __restrict__ agg2, const ushort_t* __restrict__ xin2,
    const ushort_t* __restrict__ Bsw, const float* __restrict__ bias,
    void* __restrict__ outp, int M, int out_split)
{
    __shared__ __align__(16) ushort_t Bs[4][SLICE];   // 128 KB ring -> 1 block/CU

    const int tid  = threadIdx.x;
    const int lane = tid & 63;
    const int wave = tid >> 6;          // 0..7
    const int lrow = lane & 15;
    const int quad = lane >> 4;
    const int rg   = wave >> 1;         // row-group 0..3
    const int cg   = wave & 1;          // col-group 0..1

    const int rowbase = blockIdx.x * BROWS + rg * 32;
    const int r0 = min(rowbase + lrow, M - 1);        // clamped (tail stays in-block)
    const int r1 = min(rowbase + 16 + lrow, M - 1);
    const int kq = quad * 8;
    const int ctbase = cg * WCT;        // 0 or 8

    f32x4 acc[2][WCT];
    #pragma unroll
    for (int i = 0; i < 2; i++)
        #pragma unroll
        for (int j = 0; j < WCT; j++)
            acc[i][j] = (f32x4){0.f, 0.f, 0.f, 0.f};

    bf16x8 fr[2][4];                    // A frags, parity-indexed (statically unrolled)

    // prologue issue order (oldest -> newest): B0, B1, A0, B2, A1
    // top of ks=0: vmcnt(8) forces B0,B1,A0; leaves {B2, A1} flying = steady invariant.
    stage_b_async(Bsw,             &Bs[0][0], tid);
    stage_b_async(Bsw + SLICE,     &Bs[1][0], tid);
    load_afrag(agg2, r0, r1, kq, fr[0]);
    stage_b_async(Bsw + 2 * SLICE, &Bs[2][0], tid);
    load_afrag(agg2, r0, r1, 32 + kq, fr[1]);

    #pragma unroll
    for (int ks = 0; ks < KSTEPS; ks++) {
        __builtin_amdgcn_sched_barrier(0);
        if (ks <= 13) {
            asm volatile("s_waitcnt vmcnt(8)" ::: "memory");
        } else if (ks == 14) {
            asm volatile("s_waitcnt vmcnt(4)" ::: "memory");
        } else {
            asm volatile("s_waitcnt vmcnt(0)" ::: "memory");
        }
        __builtin_amdgcn_s_barrier();
        __builtin_amdgcn_sched_barrier(0);

        // stage B[ks+3] into the ring slot freed by slice ks-1 (reads sequenced by the
        // barrier above); 3-step flight, forced complete at top of ks+2.
        if (ks + 3 < KSTEPS)
            stage_b_async(Bsw + (size_t)(ks + 3) * SLICE, &Bs[(ks + 3) & 3][0], tid);
        __builtin_amdgcn_sched_barrier(0);

        const ushort_t* bp = &Bs[ks & 3][ctbase * 512 + lane * 8];
        __builtin_amdgcn_s_setprio(1);
        #pragma unroll
        for (int j = 0; j < WCT; j++) {
            const bf16x8 bh = *(const bf16x8*)(bp + j * 512);
            const bf16x8 bl = *(const bf16x8*)(bp + 8192 + j * 512);
            acc[0][j] = MFMA16(fr[ks & 1][0], bh, acc[0][j], 0, 0, 0);
            acc[1][j] = MFMA16(fr[ks & 1][2], bh, acc[1][j], 0, 0, 0);
            acc[0][j] = MFMA16(fr[ks & 1][1], bh, acc[0][j], 0, 0, 0);
            acc[1][j] = MFMA16(fr[ks & 1][3], bh, acc[1][j], 0, 0, 0);
            acc[0][j] = MFMA16(fr[ks & 1][0], bl, acc[0][j], 0, 0, 0);
            acc[1][j] = MFMA16(fr[ks & 1][2], bl, acc[1][j], 0, 0, 0);
        }
        __builtin_amdgcn_s_setprio(0);

        // A[ks+2] overwrites fr[ks&1] (WAR on the frags orders it after the MFMA burst);
        // newest vmcnt group, flying across the next two tops, forced at top of ks+2.
        if (ks + 2 < KSTEPS) {
            const int k2 = ks + 2;
            const ushort_t* ab = (k2 < 8) ? agg2 : xin2;
            load_afrag(ab, r0, r1, (k2 & 7) * 32 + kq, fr[ks & 1]);
        }
    }

    // block-wide: all A-reads consumed before any in-place epilogue write
    __syncthreads();

    // ---- epilogue: bias (+relu+split for layers 1-2, f32 for layer 3) ----
    // C layout: col=lane&15, row=quad*4+reg. Row-outer / ct-inner: stores stream per row.
    #pragma unroll
    for (int rt = 0; rt < 2; rt++) {
        #pragma unroll
        for (int rr = 0; rr < 4; rr++) {
            const int row = rowbase + rt * 16 + quad * 4 + rr;
            if (row < M) {
                if (out_split) {
                    ushort_t* orow = (ushort_t*)outp + (size_t)row * 512;
                    #pragma unroll
                    for (int j = 0; j < WCT; j++) {
                        const int col = (ctbase + j) * 16 + lrow;
                        float v = fmaxf(acc[rt][j][rr] + bias[col], 0.f);
                        unsigned u = __float_as_uint(v);
                        float lo = v - bflo(u);
                        orow[col]       = (ushort_t)(u >> 16);
                        orow[col + 256] = (ushort_t)(__float_as_uint(lo) >> 16);
                    }
                } else {
                    float* orow = (float*)outp + (size_t)row * DIM;
                    #pragma unroll
                    for (int j = 0; j < WCT; j++) {
                        const int col = (ctbase + j) * 16 + lrow;
                        orow[col] = acc[rt][j][rr] + bias[col];
                    }
                }
            }
        }
    }
}

extern "C" void kernel_launch(void* const* d_in, const int* in_sizes, int n_in,
                              void* d_out, int out_size, void* d_ws, size_t ws_size,
                              hipStream_t stream) {
    const int*   edge = (const int*)d_in[0];
    const int*   src  = edge;
    const int*   dst  = edge + NEDGE;
    const float* x    = (const float*)d_in[1];
    const float* Wl1  = (const float*)d_in[2];
    const float* Wr1  = (const float*)d_in[3];
    const float* b1   = (const float*)d_in[4];
    const float* Wl2  = (const float*)d_in[5];
    const float* Wr2  = (const float*)d_in[6];
    const float* b2   = (const float*)d_in[7];
    const float* Wl3  = (const float*)d_in[8];
    const float* Wr3  = (const float*)d_in[9];
    const float* b3   = (const float*)d_in[10];

    // workspace: agg2 (split-plane, N*512 ushorts = 102.4 MB) + CSR + Bsw  (~109 MB total)
    ushort_t* agg2      = (ushort_t*)d_ws;
    int*      cnt       = (int*)(agg2 + (size_t)NNODES * 512);
    int*      row_start = cnt + NNODES;
    int*      cursor    = row_start + NNODES;
    int*      partial   = cursor + NNODES;            // 512
    int*      esrc      = partial + 512;              // NEDGE
    ushort_t* Bsw       = (ushort_t*)(esrc + NEDGE);  // KSTEPS*SLICE ushorts (512 KB)

    // x2 / h1 / h2 all live in the d_out region (N*512 ushorts == N*256 f32 == out_size);
    // each GEMM rewrites it in-place (block-own rows), layer 3 leaves f32 output there.
    ushort_t* x2 = (ushort_t*)d_out;

    const int nScanBlocks = (NNODES + 255) / 256;

    // ---- CSR build (edge structure shared by all 3 layers) ----
    hipMemsetAsync(cnt, 0, NNODES * sizeof(int), stream);
    hipMemsetAsync(cursor, 0, NNODES * sizeof(int), stream);
    count_kernel<<<(NEDGE + 255) / 256, 256, 0, stream>>>(dst, cnt, NEDGE);
    scan1<<<nScanBlocks, 256, 0, stream>>>(cnt, partial, NNODES);
    scan2<<<1, 512, 0, stream>>>(partial, nScanBlocks);
    scan3<<<nScanBlocks, 256, 0, stream>>>(cnt, partial, row_start, NNODES);
    fill_csr<<<(NEDGE + 255) / 256, 256, 0, stream>>>(src, dst, row_start, cursor, esrc, NEDGE);

    split_x<<<(NNODES * 64 + 255) / 256, 256, 0, stream>>>(x, x2);

    const int aggBlocks  = (NNODES * 64 + 255) / 256;
    const int gemmBlocks = (NNODES + BROWS - 1) / BROWS;
    const int convBlocks = (256 * 512 + 255) / 256;

    // ---- layer 1 ----
    conv_weights<<<convBlocks, 256, 0, stream>>>(Wl1, Wr1, Bsw);
    aggregate2<<<aggBlocks, 256, 0, stream>>>(esrc, row_start, cnt, x2, agg2);
    sage_gemm_mfma<<<gemmBlocks, 512, 0, stream>>>(agg2, x2, Bsw, b1, (void*)x2, NNODES, 1);

    // ---- layer 2 ----
    conv_weights<<<convBlocks, 256, 0, stream>>>(Wl2, Wr2, Bsw);
    aggregate2<<<aggBlocks, 256, 0, stream>>>(esrc, row_start, cnt, x2, agg2);
    sage_gemm_mfma<<<gemmBlocks, 512, 0, stream>>>(agg2, x2, Bsw, b2, (void*)x2, NNODES, 1);

    // ---- layer 3 ----
    conv_weights<<<convBlocks, 256, 0, stream>>>(Wl3, Wr3, Bsw);
    aggregate2<<<aggBlocks, 256, 0, stream>>>(esrc, row_start, cnt, x2, agg2);
    sage_gemm_mfma<<<gemmBlocks, 512, 0, stream>>>(agg2, x2, Bsw, b3, d_out, NNODES, 0);
}